// Round 7
// baseline (212.964 us; speedup 1.0000x reference)
//
#include <hip/hip_runtime.h>

typedef unsigned short ushort_t;
typedef __attribute__((ext_vector_type(8))) short bf16x8;     // 8 bf16 in 4 VGPRs
typedef __attribute__((ext_vector_type(4))) float f32x4;
typedef __attribute__((ext_vector_type(16))) float f32x16;

__device__ __forceinline__ unsigned short f2bf(float f) {
    union { float f; unsigned u; } v; v.f = f;
    unsigned r = v.u + 0x7FFFu + ((v.u >> 16) & 1u);   // RNE
    return (unsigned short)(r >> 16);
}

// v_cvt_pk_bf16_f32: lo=RNE(a), hi=RNE(b) — bit-identical to f2bf, 1 inst / 2 elems
__device__ __forceinline__ unsigned cvt_pk_bf16(float a, float b) {
    unsigned r;
    asm("v_cvt_pk_bf16_f32 %0, %1, %2" : "=v"(r) : "v"(a), "v"(b));
    return r;
}

// ================= weight prep, fragment-major, coalesced writes =================
// B-fragment layout for v_mfma_f32_32x32x16_bf16: lane = khalf*32 + r32 holds
// W[ngrp*32 + r32][kfrag*16 + khalf*8 .. +8).  Stored as
//   Wf[(ngrp*KFRAGS + kfrag)*512 + lane*8 + e]
// W1eff folds the 3x3 conv into fc1 (p indexes the 28x28 input, zero-padded to 832).
// v10: conv-fold taps are BRANCH-FREE — clamped addresses + zeroed weights, so all 9
// gathered loads issue independently (one L2 latency window, not nine serialized).
__global__ __launch_bounds__(256) void prep_w(const float* __restrict__ fc1_w,
                                              const float* __restrict__ cw,
                                              const float* __restrict__ fc2_w,
                                              const float* __restrict__ out_w,
                                              ushort_t* __restrict__ W1,
                                              ushort_t* __restrict__ W2,
                                              ushort_t* __restrict__ W3) {
    const int idx = blockIdx.x * 256 + threadIdx.x;
    // ---- W1f: 16 ngrps x 52 kfrags x 512 = 425984 elements ----
    if (idx < 425984) {
        const int ngrp = idx / 26624;              // 52*512
        const int kfrag = (idx % 26624) >> 9;
        const int li = idx & 511;
        const int lane = li >> 3, e = li & 7;
        const int n = ngrp * 32 + (lane & 31);
        const int p = kfrag * 16 + (lane >> 5) * 8 + e;
        float acc = 0.f;
        if (p < 784) {
            const int pr = p / 28, pc = p % 28;
            const float* frow = &fc1_w[n * 676];
#pragma unroll
            for (int dr = 0; dr < 3; ++dr) {
                const int r = pr - dr;
                const bool rok = (unsigned)r < 26u;
                const int rc = rok ? r : 0;
#pragma unroll
                for (int dc = 0; dc < 3; ++dc) {
                    const int c = pc - dc;
                    const bool cok = (unsigned)c < 26u;
                    const int cc = cok ? c : 0;
                    const float w = (rok && cok) ? cw[dr * 3 + dc] : 0.f;
                    acc += w * frow[rc * 26 + cc];     // always-safe address, weight 0 if pad
                }
            }
        }
        W1[idx] = f2bf(acc);
    }
    // ---- W2f: 16 ngrps x 32 kfrags x 512 = 262144 ----
    if (idx < 262144) {
        const int ngrp = idx / 16384;              // 32*512
        const int kfrag = (idx % 16384) >> 9;
        const int li = idx & 511;
        const int lane = li >> 3, e = li & 7;
        const int n = ngrp * 32 + (lane & 31);
        const int p = kfrag * 16 + (lane >> 5) * 8 + e;
        W2[idx] = f2bf(fc2_w[n * 512 + p]);
    }
    if (idx < 16 * 512)  W3[idx] = (idx < 10 * 512) ? f2bf(out_w[idx]) : (ushort_t)0;
}

// ================= fully-fused network, v10: v9 minus the spill =================
// 512 blocks x 64 batch rows, 1024 threads (16 waves). launch_bounds(1024,8): 64-reg
// budget -> 2 blocks/CU -> 8 waves/SIMD (v9 measured 72% occupancy, best mega 77us).
// v9's WRITE_SIZE=40MB exposed scratch spill under the tight budget. v10 shrinks the
// staging live range: xv (4 f32) is packed to 2 dwords MID-STEP (after ksub 2 — HBM
// latency still hides under ~384cy of MFMAs), and the LDS store is one ds_write_b64.
__global__ __launch_bounds__(1024, 8) void mega10(const float* __restrict__ x,
                                                  const ushort_t* __restrict__ W1,
                                                  const ushort_t* __restrict__ W2,
                                                  const ushort_t* __restrict__ W3,
                                                  const float* __restrict__ b1,
                                                  const float* __restrict__ b2,
                                                  const float* __restrict__ ob,
                                                  float* __restrict__ out) {
    extern __shared__ ushort_t smem[];
    ushort_t* xs0 = smem;                // [64][64]   8 KB  x buffer A (seg-swizzled)
    ushort_t* hs  = smem + 4096;         // [64][512] 64 KB h1/h2 tile; first 8KB = x buffer B

    const int tid = threadIdx.x;
    const int wave = tid >> 6, lane = tid & 63;
    const int r32 = lane & 31, khalf = lane >> 5;
    const int xrow = tid >> 4, xseg = tid & 15;         // x staging: 64 rows x 16 segs(4 cols)
    const int m0 = blockIdx.x * 64;
    const size_t ng = wave;                             // this wave's n-group (n = wave*32+r32)

    // precomputed per-thread staging addresses (constants across the loop)
    const float* xgp = &x[(size_t)(m0 + xrow) * 784 + xseg * 4];
    const int xldso = xrow * 64 + (((xseg >> 1) ^ (xrow & 7)) * 8) + (xseg & 1) * 4;

    f32x16 acc[2];                                      // [i = m-frag]; 32 AGPRs
#pragma unroll
    for (int a = 0; a < 2; ++a)
#pragma unroll
        for (int e = 0; e < 16; ++e) acc[a][e] = 0.f;

    f32x4 xv;                                           // staged x, fp32 (4 VGPR, short-lived)
    unsigned xlo, xhi;                                  // staged x, packed bf16 (2 VGPR)
    auto load_x = [&](int ks) {
        const int gc = ks * 64 + xseg * 4;
        if (gc < 784) {
            xv = __builtin_nontemporal_load((const f32x4*)(xgp + ks * 64));
        } else {
            xv = (f32x4){0.f, 0.f, 0.f, 0.f};
        }
    };
    auto cvt_x = [&]() {                                // fp32x4 -> 2 packed dwords (RNE)
        xlo = cvt_pk_bf16(xv.x, xv.y);
        xhi = cvt_pk_bf16(xv.z, xv.w);
    };
    auto write_x = [&](ushort_t* buf) {                 // one ds_write_b64
        unsigned long long v = ((unsigned long long)xhi << 32) | xlo;
        *(unsigned long long*)&buf[xldso] = v;
    };

    // h-epilogue: bias+relu -> hs (A-layout, seg' = seg ^ (m&7)); cols = this wave's 32 n
    auto write_h = [&](const float* __restrict__ bias) {
        const int n = wave * 32 + r32;
        const float bb = bias[n];
        const int nseg = n >> 3, nrem = n & 7;
#pragma unroll
        for (int i = 0; i < 2; ++i)
#pragma unroll
            for (int reg = 0; reg < 16; ++reg) {
                const int m = i * 32 + 4 * khalf + (reg & 3) + 8 * (reg >> 2);
                hs[m * 512 + ((nseg ^ (m & 7)) * 8) + nrem] = f2bf(fmaxf(acc[i][reg] + bb, 0.f));
            }
    };

    // one phase-1 K-subtile: W load + 2 LDS A reads + 2 MFMAs
    auto p1_ksub = [&](int kf, int ksub, const ushort_t* bufp) {
        const bf16x8 bw = *(const bf16x8*)&W1[(ng * 52 + kf) * 512 + lane * 8];
        const int q = 2 * ksub + khalf;
        bf16x8 af[2];
#pragma unroll
        for (int i = 0; i < 2; ++i) {
            const int m = i * 32 + r32;
            af[i] = *(const bf16x8*)&bufp[m * 64 + ((q ^ (m & 7)) * 8)];
        }
        __builtin_amdgcn_s_setprio(1);
        acc[0] = __builtin_amdgcn_mfma_f32_32x32x16_bf16(af[0], bw, acc[0], 0, 0, 0);
        acc[1] = __builtin_amdgcn_mfma_f32_32x32x16_bf16(af[1], bw, acc[1], 0, 0, 0);
        __builtin_amdgcn_s_setprio(0);
    };

    load_x(0);
    cvt_x();
    write_x(xs0);
    __syncthreads();

    // ---------------- phase 1: K = 832, 12 full steps of BK=64, 1 barrier/step ----------------
    for (int ks = 0; ks < 12; ++ks) {
        load_x(ks + 1);                                 // next x flies under the MFMAs
        const ushort_t* bufp = (ks & 1) ? hs : xs0;
        p1_ksub(ks * 4 + 0, 0, bufp);
        p1_ksub(ks * 4 + 1, 1, bufp);
        p1_ksub(ks * 4 + 2, 2, bufp);
        cvt_x();                                        // vmcnt wait lands here (~384cy after issue)
        p1_ksub(ks * 4 + 3, 3, bufp);
        write_x((ks & 1) ? xs0 : hs);                   // fill the other buffer
        __syncthreads();
    }
    // ---- step 12: only kfrag 48 is nonzero (k 768..783 real; 784..831 is zero pad) ----
    {
        const ushort_t* bufp = xs0;                     // ks=12 even -> buffer A
        const bf16x8 bw = *(const bf16x8*)&W1[(ng * 52 + 48) * 512 + lane * 8];
        const int q = khalf;
        bf16x8 af[2];
#pragma unroll
        for (int i = 0; i < 2; ++i) {
            const int m = i * 32 + r32;
            af[i] = *(const bf16x8*)&bufp[m * 64 + ((q ^ (m & 7)) * 8)];
        }
        __builtin_amdgcn_s_setprio(1);
        acc[0] = __builtin_amdgcn_mfma_f32_32x32x16_bf16(af[0], bw, acc[0], 0, 0, 0);
        acc[1] = __builtin_amdgcn_mfma_f32_32x32x16_bf16(af[1], bw, acc[1], 0, 0, 0);
        __builtin_amdgcn_s_setprio(0);
    }
    // no barrier needed: step-12 read xs0 only; h1 writes touch hs, whose last readers
    // (step 11 x-alias reads) finished before the ks=11 barrier.

    // ---- h1 = relu(acc + b1) -> hs ----
    write_h(b1);
#pragma unroll
    for (int a = 0; a < 2; ++a)
#pragma unroll
        for (int e = 0; e < 16; ++e) acc[a][e] = 0.f;
    __syncthreads();

    // ---------------- phase 2: K = 512, no intra-phase barriers ----------------
    for (int ks = 0; ks < 8; ++ks) {
#pragma unroll
        for (int ksub = 0; ksub < 4; ++ksub) {
            const int kf = ks * 4 + ksub;
            const bf16x8 bw = *(const bf16x8*)&W2[(ng * 32 + kf) * 512 + lane * 8];
            const int hq = kf * 2 + khalf;              // 16B-seg index within hs row (0..63)
            bf16x8 af[2];
#pragma unroll
            for (int i = 0; i < 2; ++i) {
                const int m = i * 32 + r32;
                af[i] = *(const bf16x8*)&hs[m * 512 + ((hq ^ (m & 7)) * 8)];
            }
            __builtin_amdgcn_s_setprio(1);
            acc[0] = __builtin_amdgcn_mfma_f32_32x32x16_bf16(af[0], bw, acc[0], 0, 0, 0);
            acc[1] = __builtin_amdgcn_mfma_f32_32x32x16_bf16(af[1], bw, acc[1], 0, 0, 0);
            __builtin_amdgcn_s_setprio(0);
        }
    }
    __syncthreads();                                    // all hs(h1) reads done

    // ---- h2 = relu(acc + b2) -> hs ----
    write_h(b2);
    __syncthreads();

    // ---------------- head: waves 0..3 -> 16 rows each, K=512, direct stores ----------------
    if (wave < 4) {
        const int quad = lane >> 4, l16 = lane & 15;
        const int row = wave * 16 + l16;
        f32x4 hacc = {0.f, 0.f, 0.f, 0.f};
#pragma unroll
        for (int ks = 0; ks < 16; ++ks) {
            const int seg = 4 * ks + quad;
            const bf16x8 a = *(const bf16x8*)&hs[row * 512 + ((seg ^ (row & 7)) * 8)];
            const bf16x8 b = *(const bf16x8*)&W3[l16 * 512 + ks * 32 + quad * 8];
            hacc = __builtin_amdgcn_mfma_f32_16x16x32_bf16(a, b, hacc, 0, 0, 0);
        }
        if (l16 < 10) {
            const float bb = ob[l16];
#pragma unroll
            for (int r = 0; r < 4; ++r)
                out[(size_t)(m0 + wave * 16 + quad * 4 + r) * 10 + l16] = hacc[r] + bb;
        }
    }
}

extern "C" void kernel_launch(void* const* d_in, const int* in_sizes, int n_in,
                              void* d_out, int out_size, void* d_ws, size_t ws_size,
                              hipStream_t stream) {
    const float* x      = (const float*)d_in[0];
    const float* conv_w = (const float*)d_in[1];
    const float* fc1_w  = (const float*)d_in[2];
    const float* fc1_b  = (const float*)d_in[3];
    const float* fc2_w  = (const float*)d_in[4];
    const float* fc2_b  = (const float*)d_in[5];
    const float* out_w  = (const float*)d_in[6];
    const float* out_b  = (const float*)d_in[7];
    float* out = (float*)d_out;

    // workspace: W1f | W2f | W3 (≈1.4 MB total), fragment-major layouts
    ushort_t* W1 = (ushort_t*)d_ws;                    // 16*52*512
    ushort_t* W2 = W1 + 425984;                        // 16*32*512
    ushort_t* W3 = W2 + 262144;                        // 16*512

    prep_w<<<dim3(1664), 256, 0, stream>>>(fc1_w, conv_w, fc2_w, out_w, W1, W2, W3);

    // 512 blocks x 64 rows; 1024 threads (16 waves); 72 KB dynamic LDS;
    // launch_bounds(1024,8): 64-reg budget -> 2 blocks/CU -> 8 waves/SIMD
    mega10<<<dim3(512), 1024, 73728, stream>>>(x, W1, W2, W3, fc1_b, fc2_b, out_b, out);
}